// Round 8
// baseline (187.279 us; speedup 1.0000x reference)
//
#include <hip/hip_runtime.h>
#include <hip/hip_fp16.h>

typedef _Float16 f16;
typedef _Float16 f16x8 __attribute__((ext_vector_type(8)));
typedef float f32x4 __attribute__((ext_vector_type(4)));

__device__ __forceinline__ f16x8 relu8(f16x8 a) {
#if __has_builtin(__builtin_elementwise_max)
  return __builtin_elementwise_max(a, (f16x8)(f16)0);   // v_pk_max_f16 x4
#else
  f16x8 r;
#pragma unroll
  for (int i = 0; i < 8; i++) r[i] = a[i] > (f16)0 ? a[i] : (f16)0;
  return r;
#endif
}

__device__ __forceinline__ f16x8 bcast8(f16 s) {
  return (f16x8){s, s, s, s, s, s, s, s};
}

// ---------------------------------------------------------------------------
// prep: Wtp[frag=cg*32+kb2][lane*8+e] = f16(W2[kb2*32+q*8+e][cg*16+cL])
// (B-fragment order for mfma_f32_16x16x32_f16; 1 KB contiguous per fragment;
//  n-quarter nq's slice = Wtp[nq*32768 ..] is 64 KB contiguous)
// ---------------------------------------------------------------------------
__global__ __launch_bounds__(256) void k_prep(const float* __restrict__ W2,
                                              f16* __restrict__ Wtp) {
  const int t = blockIdx.x * 256 + threadIdx.x;
  const int frag = t >> 6, l = t & 63;
  const int cg = frag >> 5, kb2 = frag & 31;
  const int q = l >> 4, cL = l & 15;
  const int n = cg * 16 + cL, k0 = kb2 * 32 + q * 8;
  f16x8 o;
#pragma unroll
  for (int e = 0; e < 8; e++) o[e] = (f16)W2[(k0 + e) * 128 + n];
  *(f16x8*)(Wtp + frag * 512 + l * 8) = o;
}

// ---------------------------------------------------------------------------
// fused: block = (jt, strip of 8 i, nq), 256 threads = 4 waves, 2 blocks/CU.
// W2 n-quarter (32 n x 1024 k = 64 KB) staged to LDS once; K-loop reads LDS
// with 1-deep register prefetch of B-fragments; A-fragments regenerated in
// registers: relu(xj*w1b + (xi*w1a + b1)). Each wave: 2 i-rows interleaved.
// launch_bounds(256,2): 2 blocks/CU, 256 VGPR/wave budget -> no spill
// (R6 lesson: watch WRITE_SIZE for the spill signature).
// ---------------------------------------------------------------------------
__global__ __launch_bounds__(256, 2) void k_fused(
    const float* __restrict__ x, const float* __restrict__ W1,
    const float* __restrict__ b1, const float* __restrict__ b2,
    const float* __restrict__ W3, const float* __restrict__ b3,
    const f16* __restrict__ Wtp,
    float* __restrict__ Kp0, float* __restrict__ Kp1,
    float* __restrict__ Kp2, float* __restrict__ Kp3) {
  __shared__ f16 w2f[32768];                 // 64 KB: this nq's B-fragments
  __shared__ f16 w1a[1024], w1bt[1024], b1t[1024];

  const int tid = threadIdx.x;
  const int jt = blockIdx.x, s = blockIdx.y, nq = blockIdx.z;
  const int i0 = s * 8, j0 = jt * 128;
  if (i0 > j0 + 127) return;                 // strip entirely below diagonal
  float* __restrict__ Kp = (nq == 0) ? Kp0 : (nq == 1) ? Kp1
                         : (nq == 2) ? Kp2 : Kp3;

  // --- stage W2 quarter: contiguous 64 KB slice of Wtp
  {
    const f16* src = Wtp + nq * 32768;
    #pragma unroll
    for (int p = 0; p < 16; p++) {
      const int off = p * 2048 + tid * 8;
      *(f16x8*)(&w2f[off]) = *(const f16x8*)(src + off);
    }
  }
  // --- stage W1 row tables (f16)
  if (tid < 128) {
    const int c8 = tid << 3;
    const float4 a0 = *(const float4*)(W1 + c8);
    const float4 a1 = *(const float4*)(W1 + c8 + 4);
    const float4 g0 = *(const float4*)(b1 + c8);
    const float4 g1 = *(const float4*)(b1 + c8 + 4);
    f16x8 oa, og;
    oa[0] = (f16)a0.x; oa[1] = (f16)a0.y; oa[2] = (f16)a0.z; oa[3] = (f16)a0.w;
    oa[4] = (f16)a1.x; oa[5] = (f16)a1.y; oa[6] = (f16)a1.z; oa[7] = (f16)a1.w;
    og[0] = (f16)g0.x; og[1] = (f16)g0.y; og[2] = (f16)g0.z; og[3] = (f16)g0.w;
    og[4] = (f16)g1.x; og[5] = (f16)g1.y; og[6] = (f16)g1.z; og[7] = (f16)g1.w;
    *(f16x8*)(&w1a[c8]) = oa;
    *(f16x8*)(&b1t[c8]) = og;
  } else {
    const int c8 = (tid - 128) << 3;
    const float4 a0 = *(const float4*)(W1 + 1024 + c8);
    const float4 a1 = *(const float4*)(W1 + 1024 + c8 + 4);
    f16x8 ob;
    ob[0] = (f16)a0.x; ob[1] = (f16)a0.y; ob[2] = (f16)a0.z; ob[3] = (f16)a0.w;
    ob[4] = (f16)a1.x; ob[5] = (f16)a1.y; ob[6] = (f16)a1.z; ob[7] = (f16)a1.w;
    *(f16x8*)(&w1bt[c8]) = ob;
  }
  __syncthreads();

  const int lane = tid & 63, wv = tid >> 6;  // 4 waves; wave owns 2 i-rows
  const int cL = lane & 15, q = lane >> 4;
  const int ia = i0 + wv * 2, ib = ia + 1;

  // per-lane x_j for the 8 j-groups (A-frag m-index = cL)
  f16 xjs[8];
  #pragma unroll
  for (int rg = 0; rg < 8; rg++) xjs[rg] = (f16)x[j0 + rg * 16 + cL];

  float b2v[2], w3v[2];
  #pragma unroll
  for (int cg = 0; cg < 2; cg++) {
    b2v[cg] = b2[nq * 32 + cg * 16 + cL];
    w3v[cg] = W3[nq * 32 + cg * 16 + cL];
  }
  const float badd = (nq == 0) ? b3[0] : 0.f;  // b3 added exactly once
  const f16x8 xav = bcast8((f16)x[ia]);
  const f16x8 xbv = bcast8((f16)x[ib]);

  f32x4 acc[2][8][2];                        // [ii][rg][cg] = 128 VGPR
  #pragma unroll
  for (int ii = 0; ii < 2; ii++)
    #pragma unroll
    for (int rg = 0; rg < 8; rg++)
      #pragma unroll
      for (int cg = 0; cg < 2; cg++) acc[ii][rg][cg] = (f32x4){0.f, 0.f, 0.f, 0.f};

  // B-fragment register prefetch (1-deep): hide ds_read latency under MFMAs
  f16x8 bcur[2], bnxt[2];
  #pragma unroll
  for (int cg = 0; cg < 2; cg++)
    bcur[cg] = *(const f16x8*)(&w2f[(cg * 32) * 512 + lane * 8]);

  for (int kk = 0; kk < 32; ++kk) {
    const int kn = (kk + 1) & 31;
    #pragma unroll
    for (int cg = 0; cg < 2; cg++)
      bnxt[cg] = *(const f16x8*)(&w2f[(cg * 32 + kn) * 512 + lane * 8]);
    const int o = kk * 32 + q * 8;
    const f16x8 w1av = *(const f16x8*)(&w1a[o]);
    const f16x8 b1v  = *(const f16x8*)(&b1t[o]);
    const f16x8 w1bv = *(const f16x8*)(&w1bt[o]);
    const f16x8 hava = xav * w1av + b1v;       // v_pk_fma_f16 x4
    const f16x8 havb = xbv * w1av + b1v;
    #pragma unroll
    for (int rg = 0; rg < 8; rg++) {
      const f16x8 xjv = bcast8(xjs[rg]);
      const f16x8 afa = relu8(xjv * w1bv + hava);
      const f16x8 afb = relu8(xjv * w1bv + havb);
      #pragma unroll
      for (int cg = 0; cg < 2; cg++) {
        acc[0][rg][cg] = __builtin_amdgcn_mfma_f32_16x16x32_f16(afa, bcur[cg], acc[0][rg][cg], 0, 0, 0);
        acc[1][rg][cg] = __builtin_amdgcn_mfma_f32_16x16x32_f16(afb, bcur[cg], acc[1][rg][cg], 0, 0, 0);
      }
    }
    bcur[0] = bnxt[0]; bcur[1] = bnxt[1];
  }

  // --- epilogue: partial dot over this nq's 32 n for both i-rows
  #pragma unroll
  for (int ii = 0; ii < 2; ii++) {
    const int i = ia + ii;
    #pragma unroll
    for (int rg = 0; rg < 8; rg++) {
      #pragma unroll
      for (int r = 0; r < 4; r++) {
        float ssum = 0.f;
        #pragma unroll
        for (int cg = 0; cg < 2; cg++)
          ssum = fmaf(fmaxf(acc[ii][rg][cg][r] + b2v[cg], 0.f), w3v[cg], ssum);
        ssum += __shfl_xor(ssum, 1, 64);
        ssum += __shfl_xor(ssum, 2, 64);
        ssum += __shfl_xor(ssum, 4, 64);
        ssum += __shfl_xor(ssum, 8, 64);
        if (cL == 0) {
          const int j = j0 + rg * 16 + q * 4 + r;  // C row = q*4 + reg
          if (j >= i) Kp[i * 512 + j] = ssum + badd;
        }
      }
    }
  }
}

// ---------------------------------------------------------------------------
// atta: C = K^T K, K = Kp0+Kp1+Kp2+Kp3 (summed on load). Below-diagonal
// entries UNWRITTEN -> masked to 0. Symmetry (pb<=qb + mirror), i <= pb+31.
// ---------------------------------------------------------------------------
__global__ __launch_bounds__(256) void k_atta(const float* __restrict__ K0,
                                              const float* __restrict__ K1,
                                              const float* __restrict__ K2,
                                              const float* __restrict__ K3,
                                              float* __restrict__ C) {
  const int pb = blockIdx.x * 32, qb = blockIdx.y * 32;
  if (pb > qb) return;
  __shared__ float sp[32][33], sq[32][33];
  const int tid = threadIdx.x;
  const int tx = tid & 15, ty = tid >> 4;
  float c00 = 0.f, c01 = 0.f, c10 = 0.f, c11 = 0.f;
  for (int i0 = 0; i0 < pb + 32; i0 += 32) {
    #pragma unroll
    for (int r = 0; r < 4; r++) {
      const int e = tid + 256 * r, ii = e >> 5, pp = e & 31;
      const int irow = i0 + ii;
      const int ip = irow * 512 + pb + pp, iq = irow * 512 + qb + pp;
      sp[ii][pp] = (irow <= pb + pp) ? K0[ip] + K1[ip] + K2[ip] + K3[ip] : 0.f;
      sq[ii][pp] = (irow <= qb + pp) ? K0[iq] + K1[iq] + K2[iq] + K3[iq] : 0.f;
    }
    __syncthreads();
    #pragma unroll 8
    for (int ii = 0; ii < 32; ii++) {
      const float a0 = sp[ii][ty * 2], a1 = sp[ii][ty * 2 + 1];
      const float b0 = sq[ii][tx * 2], b1 = sq[ii][tx * 2 + 1];
      c00 = fmaf(a0, b0, c00); c01 = fmaf(a0, b1, c01);
      c10 = fmaf(a1, b0, c10); c11 = fmaf(a1, b1, c11);
    }
    __syncthreads();
  }
  const int p0 = pb + ty * 2, q0 = qb + tx * 2;
  C[p0 * 512 + q0] = c00;       C[p0 * 512 + q0 + 1] = c01;
  C[(p0 + 1) * 512 + q0] = c10; C[(p0 + 1) * 512 + q0 + 1] = c11;
  C[q0 * 512 + p0] = c00;       C[(q0 + 1) * 512 + p0] = c01;
  C[q0 * 512 + p0 + 1] = c10;   C[(q0 + 1) * 512 + p0 + 1] = c11;
}

extern "C" void kernel_launch(void* const* d_in, const int* in_sizes, int n_in,
                              void* d_out, int out_size, void* d_ws, size_t ws_size,
                              hipStream_t stream) {
  const float* x  = (const float*)d_in[0];
  const float* W1 = (const float*)d_in[1];
  const float* b1 = (const float*)d_in[2];
  const float* W2 = (const float*)d_in[3];
  const float* b2 = (const float*)d_in[4];
  const float* W3 = (const float*)d_in[5];
  const float* b3 = (const float*)d_in[6];
  float* out = (float*)d_out;
  char* ws = (char*)d_ws;

  f16* Wtp = (f16*)ws;                              // 256 KB packed W2 B-fragments
  float* Kp0 = (float*)(ws + (256 << 10));          // 4x 1 MB partial K (n-quarters)
  float* Kp1 = (float*)(ws + (256 << 10) + (1 << 20));
  float* Kp2 = (float*)(ws + (256 << 10) + (2 << 20));
  float* Kp3 = (float*)(ws + (256 << 10) + (3 << 20));

  k_prep<<<64, 256, 0, stream>>>(W2, Wtp);
  k_fused<<<dim3(4, 64, 4), 256, 0, stream>>>(x, W1, b1, b2, W3, b3, Wtp,
                                              Kp0, Kp1, Kp2, Kp3);
  k_atta<<<dim3(16, 16), 256, 0, stream>>>(Kp0, Kp1, Kp2, Kp3, out);
}

// Round 9
// 157.363 us; speedup vs baseline: 1.1901x; 1.1901x over previous
//
#include <hip/hip_runtime.h>
#include <hip/hip_fp16.h>

typedef _Float16 f16;
typedef _Float16 f16x8 __attribute__((ext_vector_type(8)));
typedef float f32x4 __attribute__((ext_vector_type(4)));

__device__ __forceinline__ f16x8 relu8(f16x8 a) {
#if __has_builtin(__builtin_elementwise_max)
  return __builtin_elementwise_max(a, (f16x8)(f16)0);   // v_pk_max_f16 x4
#else
  f16x8 r;
#pragma unroll
  for (int i = 0; i < 8; i++) r[i] = a[i] > (f16)0 ? a[i] : (f16)0;
  return r;
#endif
}

__device__ __forceinline__ f16x8 bcast8(f16 s) {
  return (f16x8){s, s, s, s, s, s, s, s};
}

// ---------------------------------------------------------------------------
// prep: Wtp[frag=cg*32+kb2][lane*8+e] = f16(W2[kb2*32+q*8+e][cg*16+cL])
// (B-fragment order for mfma_f32_16x16x32_f16; 1 KB contiguous per fragment;
//  n-half nh's slice = Wtp[nh*65536 ..] is 128 KB contiguous)
// ---------------------------------------------------------------------------
__global__ __launch_bounds__(256) void k_prep(const float* __restrict__ W2,
                                              f16* __restrict__ Wtp) {
  const int t = blockIdx.x * 256 + threadIdx.x;
  const int frag = t >> 6, l = t & 63;
  const int cg = frag >> 5, kb2 = frag & 31;
  const int q = l >> 4, cL = l & 15;
  const int n = cg * 16 + cL, k0 = kb2 * 32 + q * 8;
  f16x8 o;
#pragma unroll
  for (int e = 0; e < 8; e++) o[e] = (f16)W2[(k0 + e) * 128 + n];
  *(f16x8*)(Wtp + frag * 512 + l * 8) = o;
}

// ---------------------------------------------------------------------------
// fused: 256 PERSISTENT blocks (1/CU), 512 thr = 8 waves. Static task list:
// 640 tasks (nh-major), task = (nh, jt, s4) -> 4 i x 128 j x 64 n x 1024 k.
// W2 n-half (128 KB) re-staged to LDS only when nh changes (<=1 per block).
// Per task: hat[4i][1024k] = f16(xi*W1a+b1) built in LDS once; K-loop reads
// (hat, w1b, 4x bf) with full 1-deep register prefetch; A-frags regenerated
// in registers: relu(xj*w1b + hat). Wave = (il in 4 i's) x (jh in 2 j-halves),
// rg=4 (64 j), cg=4 (64 n), acc 64 VGPR.
// R6/R8 lessons: watch WRITE_SIZE for spill; keep cg>=4 for af amortization.
// ---------------------------------------------------------------------------
__global__ __launch_bounds__(512, 2) void k_fused(
    const float* __restrict__ x, const float* __restrict__ W1,
    const float* __restrict__ b1, const float* __restrict__ b2,
    const float* __restrict__ W3, const float* __restrict__ b3,
    const f16* __restrict__ Wtp,
    float* __restrict__ Kp0, float* __restrict__ Kp1) {
  __shared__ f16 w2f[65536];                 // 128 KB: current nh's B-fragments
  __shared__ f16 w1af[1024], b1f[1024], w1bf[1024];
  __shared__ f16 hat[4 * 1024];              // 8 KB: ha for this task's 4 i

  const int tid = threadIdx.x;

  // --- stage W1 row tables once (f16)
  if (tid < 128) {
    const int c8 = tid << 3;
    const float4 a0 = *(const float4*)(W1 + c8);
    const float4 a1 = *(const float4*)(W1 + c8 + 4);
    const float4 g0 = *(const float4*)(b1 + c8);
    const float4 g1 = *(const float4*)(b1 + c8 + 4);
    f16x8 oa, og;
    oa[0] = (f16)a0.x; oa[1] = (f16)a0.y; oa[2] = (f16)a0.z; oa[3] = (f16)a0.w;
    oa[4] = (f16)a1.x; oa[5] = (f16)a1.y; oa[6] = (f16)a1.z; oa[7] = (f16)a1.w;
    og[0] = (f16)g0.x; og[1] = (f16)g0.y; og[2] = (f16)g0.z; og[3] = (f16)g0.w;
    og[4] = (f16)g1.x; og[5] = (f16)g1.y; og[6] = (f16)g1.z; og[7] = (f16)g1.w;
    *(f16x8*)(&w1af[c8]) = oa;
    *(f16x8*)(&b1f[c8]) = og;
  } else if (tid < 256) {
    const int c8 = (tid - 128) << 3;
    const float4 a0 = *(const float4*)(W1 + 1024 + c8);
    const float4 a1 = *(const float4*)(W1 + 1024 + c8 + 4);
    f16x8 ob;
    ob[0] = (f16)a0.x; ob[1] = (f16)a0.y; ob[2] = (f16)a0.z; ob[3] = (f16)a0.w;
    ob[4] = (f16)a1.x; ob[5] = (f16)a1.y; ob[6] = (f16)a1.z; ob[7] = (f16)a1.w;
    *(f16x8*)(&w1bf[c8]) = ob;
  }

  const int lane = tid & 63, wv = tid >> 6;
  const int il = wv & 3, jh = wv >> 2;       // wave = (i-local, j-half)
  const int cL = lane & 15, q = lane >> 4;

  int cur_nh = -1;

  for (int t = (int)blockIdx.x; t < 640; t += 256) {
    const int nh = (t >= 320) ? 1 : 0;
    const int u = t - nh * 320;
    int jt, s4;
    if (u < 32)       { jt = 0; s4 = u; }
    else if (u < 96)  { jt = 1; s4 = u - 32; }
    else if (u < 192) { jt = 2; s4 = u - 96; }
    else              { jt = 3; s4 = u - 192; }
    const int i0 = s4 * 4, j0 = jt * 128;
    float* __restrict__ Kp = nh ? Kp1 : Kp0;

    __syncthreads();   // prior task's LDS reads done (also covers w1 staging)
    if (nh != cur_nh) {
      const f16* src = Wtp + nh * 65536;
      #pragma unroll
      for (int p = 0; p < 16; p++) {
        const int off = p * 4096 + tid * 8;
        *(f16x8*)(&w2f[off]) = *(const f16x8*)(src + off);
      }
      cur_nh = nh;
    }
    {  // build hat for this task's 4 i rows: hat[il][k] = xi*w1a[k] + b1[k]
      const int il_s = tid >> 7, k8 = (tid & 127) << 3;
      const f16x8 wa = *(const f16x8*)(&w1af[k8]);
      const f16x8 bb = *(const f16x8*)(&b1f[k8]);
      const f16x8 xv = bcast8((f16)x[i0 + il_s]);
      *(f16x8*)(&hat[il_s * 1024 + k8]) = xv * wa + bb;
    }
    __syncthreads();

    // per-lane x_j for this wave's 4 j-groups
    f16 xjs[4];
    #pragma unroll
    for (int rg = 0; rg < 4; rg++)
      xjs[rg] = (f16)x[j0 + jh * 64 + rg * 16 + cL];

    f32x4 acc[4][4];
    #pragma unroll
    for (int rg = 0; rg < 4; rg++)
      #pragma unroll
      for (int cg = 0; cg < 4; cg++) acc[rg][cg] = (f32x4){0.f, 0.f, 0.f, 0.f};

    const f16* hrow  = hat + il * 1024 + q * 8;
    const f16* wrow  = w1bf + q * 8;
    const f16* bbase = w2f + lane * 8;

    // prologue: kk=0 operands
    f16x8 hv_c = *(const f16x8*)(hrow);
    f16x8 wb_c = *(const f16x8*)(wrow);
    f16x8 bf_c[4];
    #pragma unroll
    for (int cg = 0; cg < 4; cg++)
      bf_c[cg] = *(const f16x8*)(bbase + (cg * 32) * 512);

    for (int kk = 0; kk < 32; ++kk) {
      f16x8 hv_n, wb_n, bf_n[4];
      const int kn = kk + 1;
      if (kn < 32) {   // issue next-iter loads before this iter's compute
        hv_n = *(const f16x8*)(hrow + kn * 32);
        wb_n = *(const f16x8*)(wrow + kn * 32);
        #pragma unroll
        for (int cg = 0; cg < 4; cg++)
          bf_n[cg] = *(const f16x8*)(bbase + (cg * 32 + kn) * 512);
      }
      f16x8 af[4];
      #pragma unroll
      for (int rg = 0; rg < 4; rg++)
        af[rg] = relu8(bcast8(xjs[rg]) * wb_c + hv_c);
      #pragma unroll
      for (int cg = 0; cg < 4; cg++)
        #pragma unroll
        for (int rg = 0; rg < 4; rg++)
          acc[rg][cg] = __builtin_amdgcn_mfma_f32_16x16x32_f16(af[rg], bf_c[cg], acc[rg][cg], 0, 0, 0);
      hv_c = hv_n; wb_c = wb_n;
      #pragma unroll
      for (int cg = 0; cg < 4; cg++) bf_c[cg] = bf_n[cg];
    }

    // --- epilogue: partial dot over this nh's 64 n
    float b2v[4], w3v[4];
    #pragma unroll
    for (int cg = 0; cg < 4; cg++) {
      b2v[cg] = b2[nh * 64 + cg * 16 + cL];
      w3v[cg] = W3[nh * 64 + cg * 16 + cL];
    }
    const float badd = (nh == 0) ? b3[0] : 0.f;  // b3 added exactly once
    const int i = i0 + il;
    #pragma unroll
    for (int rg = 0; rg < 4; rg++) {
      #pragma unroll
      for (int r = 0; r < 4; r++) {
        float ssum = 0.f;
        #pragma unroll
        for (int cg = 0; cg < 4; cg++)
          ssum = fmaf(fmaxf(acc[rg][cg][r] + b2v[cg], 0.f), w3v[cg], ssum);
        ssum += __shfl_xor(ssum, 1, 64);
        ssum += __shfl_xor(ssum, 2, 64);
        ssum += __shfl_xor(ssum, 4, 64);
        ssum += __shfl_xor(ssum, 8, 64);
        if (cL == 0) {
          const int j = j0 + jh * 64 + rg * 16 + q * 4 + r;  // C row = q*4+reg
          if (j >= i) Kp[i * 512 + j] = ssum + badd;
        }
      }
    }
  }
}

// ---------------------------------------------------------------------------
// atta: C = K^T K, K = Kp0 + Kp1 (summed on load). Below-diagonal entries
// UNWRITTEN -> masked to 0. Symmetry (pb<=qb + mirror), i-loop stops at pb+32.
// ---------------------------------------------------------------------------
__global__ __launch_bounds__(256) void k_atta(const float* __restrict__ K0,
                                              const float* __restrict__ K1,
                                              float* __restrict__ C) {
  const int pb = blockIdx.x * 32, qb = blockIdx.y * 32;
  if (pb > qb) return;
  __shared__ float sp[32][33], sq[32][33];
  const int tid = threadIdx.x;
  const int tx = tid & 15, ty = tid >> 4;
  float c00 = 0.f, c01 = 0.f, c10 = 0.f, c11 = 0.f;
  for (int i0 = 0; i0 < pb + 32; i0 += 32) {
    #pragma unroll
    for (int r = 0; r < 4; r++) {
      const int e = tid + 256 * r, ii = e >> 5, pp = e & 31;
      const int irow = i0 + ii;
      const int ip = irow * 512 + pb + pp, iq = irow * 512 + qb + pp;
      sp[ii][pp] = (irow <= pb + pp) ? K0[ip] + K1[ip] : 0.f;
      sq[ii][pp] = (irow <= qb + pp) ? K0[iq] + K1[iq] : 0.f;
    }
    __syncthreads();
    #pragma unroll 8
    for (int ii = 0; ii < 32; ii++) {
      const float a0 = sp[ii][ty * 2], a1 = sp[ii][ty * 2 + 1];
      const float b0 = sq[ii][tx * 2], b1 = sq[ii][tx * 2 + 1];
      c00 = fmaf(a0, b0, c00); c01 = fmaf(a0, b1, c01);
      c10 = fmaf(a1, b0, c10); c11 = fmaf(a1, b1, c11);
    }
    __syncthreads();
  }
  const int p0 = pb + ty * 2, q0 = qb + tx * 2;
  C[p0 * 512 + q0] = c00;       C[p0 * 512 + q0 + 1] = c01;
  C[(p0 + 1) * 512 + q0] = c10; C[(p0 + 1) * 512 + q0 + 1] = c11;
  C[q0 * 512 + p0] = c00;       C[(q0 + 1) * 512 + p0] = c01;
  C[q0 * 512 + p0 + 1] = c10;   C[(q0 + 1) * 512 + p0 + 1] = c11;
}

extern "C" void kernel_launch(void* const* d_in, const int* in_sizes, int n_in,
                              void* d_out, int out_size, void* d_ws, size_t ws_size,
                              hipStream_t stream) {
  const float* x  = (const float*)d_in[0];
  const float* W1 = (const float*)d_in[1];
  const float* b1 = (const float*)d_in[2];
  const float* W2 = (const float*)d_in[3];
  const float* b2 = (const float*)d_in[4];
  const float* W3 = (const float*)d_in[5];
  const float* b3 = (const float*)d_in[6];
  float* out = (float*)d_out;
  char* ws = (char*)d_ws;

  f16* Wtp = (f16*)ws;                              // 256 KB packed W2 B-fragments
  float* Kp0 = (float*)(ws + (256 << 10));          // 1 MB partial K (n 0..63)
  float* Kp1 = (float*)(ws + (256 << 10) + (1 << 20));  // 1 MB partial K (n 64..127)

  k_prep<<<64, 256, 0, stream>>>(W2, Wtp);
  k_fused<<<256, 512, 0, stream>>>(x, W1, b1, b2, W3, b3, Wtp, Kp0, Kp1);
  k_atta<<<dim3(16, 16), 256, 0, stream>>>(Kp0, Kp1, out);
}